// Round 6
// baseline (72.429 us; speedup 1.0000x reference)
//
#include <hip/hip_runtime.h>

// Problem constants (fixed by the reference):
//   input:  (1, 256, 512, 512) f32
//   state:  (1, 256, 256, 256) f32
//   change: (32768,) i32 flat spatial indices y*W + x
#define C_  256
#define H_  512
#define W_  512
#define OH_ 256
#define OW_ 256
// mask: 1 bit per output spatial pixel -> OH*OW/32 = 2048 u32 = 8 KB (in d_ws)

typedef float f4 __attribute__((ext_vector_type(4)));

__device__ __forceinline__ f4 ntload4(const float* p) {
    return __builtin_nontemporal_load(reinterpret_cast<const f4*>(p));
}
__device__ __forceinline__ void ntstore4(float* p, f4 v) {
    __builtin_nontemporal_store(v, reinterpret_cast<f4*>(p));
}

// Single-workgroup mask builder, 1024 threads (16 waves on one CU).
// All 8 int4 index loads issued INDEPENDENTLY up front (one latency round
// trip instead of 8 serialized load->atomic->load chains), then LDS
// atomicOr scatter, then uint4 dump of the 8 KB mask.
__global__ void __launch_bounds__(1024)
cbpool_build_mask(const int* __restrict__ change,
                  unsigned int* __restrict__ mask) {
    __shared__ unsigned int lmask[OH_ * OW_ / 32];   // 2048 words = 8 KB
    lmask[threadIdx.x]        = 0u;
    lmask[threadIdx.x + 1024] = 0u;
    __syncthreads();

    // K = 32768 fixed -> 8192 int4 -> 8 per thread
    const int4* c4 = reinterpret_cast<const int4*>(change);
    int4 v[8];
    #pragma unroll
    for (int i = 0; i < 8; ++i)
        v[i] = c4[threadIdx.x + (i << 10)];      // independent loads, one waitcnt

    #pragma unroll
    for (int i = 0; i < 8; ++i) {
        #pragma unroll
        for (int j = 0; j < 4; ++j) {
            int idx = (j == 0) ? v[i].x : (j == 1) ? v[i].y : (j == 2) ? v[i].z : v[i].w;
            int y = idx >> 9;            // W = 512 = 2^9
            int x = idx & (W_ - 1);
            int bit = (y >> 1) * OW_ + (x >> 1);
            atomicOr(&lmask[bit >> 5], 1u << (bit & 31));
        }
    }
    __syncthreads();

    // dump 2048 words with 512 uint4 stores (first 512 threads)
    if (threadIdx.x < 512) {
        reinterpret_cast<uint4*>(mask)[threadIdx.x] =
            reinterpret_cast<const uint4*>(lmask)[threadIdx.x];
    }
}

// Round-2 fused kernel (best measured): one thread per QUAD of horizontally-
// adjacent output pixels. 4x dwordx4 input, f4 state, f4 out, 1 mask word.
// All bulk traffic non-temporal (streamed once, working set >> LLC).
__global__ void __launch_bounds__(256)
cbpool_fused(const float* __restrict__ in,
             const float* __restrict__ state,
             const unsigned int* __restrict__ mask,
             float* __restrict__ out) {
    int tid = blockIdx.x * blockDim.x + threadIdx.x;   // 0 .. C*OH*(OW/4)-1
    int q  = tid & 63;                 // quad index along output row, 0..63
    int oy = (tid >> 6) & (OH_ - 1);   // output row
    int c  = tid >> 14;                // channel

    // input row pair base: c*H*W + (2*oy)*W + 8*q
    const float* inrow = in + ((size_t)c << 18) + ((size_t)oy << 10) + (q << 3);
    f4 a0 = ntload4(inrow);
    f4 a1 = ntload4(inrow + 4);
    f4 b0 = ntload4(inrow + W_);
    f4 b1 = ntload4(inrow + W_ + 4);

    f4 pooled;
    pooled.x = fmaxf(fmaxf(a0.x, a0.y), fmaxf(b0.x, b0.y));
    pooled.y = fmaxf(fmaxf(a0.z, a0.w), fmaxf(b0.z, b0.w));
    pooled.z = fmaxf(fmaxf(a1.x, a1.y), fmaxf(b1.x, b1.y));
    pooled.w = fmaxf(fmaxf(a1.z, a1.w), fmaxf(b1.z, b1.w));

    size_t obase = ((size_t)c << 16) + (oy << 8) + (q << 2);
    f4 s = ntload4(state + obase);

    unsigned int m = mask[(oy << 3) + (q >> 3)];   // 4 bits for this quad share a word
    int sh = (q << 2) & 31;

    f4 o;
    o.x = ((m >> (sh + 0)) & 1u) ? pooled.x : s.x;
    o.y = ((m >> (sh + 1)) & 1u) ? pooled.y : s.y;
    o.z = ((m >> (sh + 2)) & 1u) ? pooled.z : s.z;
    o.w = ((m >> (sh + 3)) & 1u) ? pooled.w : s.w;
    ntstore4(out + obase, o);
}

extern "C" void kernel_launch(void* const* d_in, const int* in_sizes, int n_in,
                              void* d_out, int out_size, void* d_ws, size_t ws_size,
                              hipStream_t stream) {
    const float* in     = (const float*)d_in[0];
    const float* state  = (const float*)d_in[1];
    const int*   change = (const int*)d_in[2];
    float*       out    = (float*)d_out;
    unsigned int* mask  = (unsigned int*)d_ws;   // 8 KB used

    cbpool_build_mask<<<1, 1024, 0, stream>>>(change, mask);

    const int total_quads = C_ * OH_ * (OW_ / 4);      // 4,194,304
    cbpool_fused<<<total_quads / 256, 256, 0, stream>>>(in, state, mask, out);
}